// Round 14
// baseline (1442.438 us; speedup 1.0000x reference)
//
#include <hip/hip_runtime.h>
#include <cstdint>
#include <math.h>

// Problem sizes (fixed by the reference).
#define NN 50000
#define EE 800000
#define RR 850000      // NN + EE rows
#define NT_N 3125      // NN/16
#define NT_R 53125     // RR/16
#define NCH 3125       // EE/256 chunks for bucket sort
#define NBUK 4         // src buckets: b = src/12500 -> u slice 3.2 MB < 4 MB XCD L2

typedef short  bf16x8 __attribute__((ext_vector_type(8)));
typedef float  f32x4  __attribute__((ext_vector_type(4)));

__device__ __forceinline__ float bf2f(unsigned short b) {
    unsigned int u = ((unsigned int)b) << 16;
    return __builtin_bit_cast(float, u);
}
__device__ __forceinline__ unsigned short f2bf(float f) {
    unsigned int u = __builtin_bit_cast(unsigned int, f);
    u = u + 0x7fffu + ((u >> 16) & 1u);
    return (unsigned short)(u >> 16);
}
__device__ __forceinline__ void atomAddF(float* p, float v) { unsafeAtomicAdd(p, v); }
__device__ __forceinline__ void atomAddD(double* p, double v) { unsafeAtomicAdd(p, v); }
__device__ __forceinline__ int atomAddI(int* p, int v) { return atomicAdd(p, v); }

// split 8 consecutive f32 into hi/lo bf16 fragments: hi+lo == v to ~2^-16 rel
__device__ __forceinline__ void split8(const float* p, bf16x8& hi, bf16x8& lo) {
    f32x4 v0 = *reinterpret_cast<const f32x4*>(p);
    f32x4 v1 = *reinterpret_cast<const f32x4*>(p + 4);
#pragma unroll
    for (int j = 0; j < 4; j++) {
        unsigned short h0 = f2bf(v0[j]);
        hi[j] = (short)h0; lo[j] = (short)f2bf(v0[j] - bf2f(h0));
        unsigned short h1 = f2bf(v1[j]);
        hi[4 + j] = (short)h1; lo[4 + j] = (short)f2bf(v1[j] - bf2f(h1));
    }
}
__device__ __forceinline__ void split8r(const float* v, bf16x8& hi, bf16x8& lo) {
#pragma unroll
    for (int j = 0; j < 8; j++) {
        unsigned short h = f2bf(v[j]);
        hi[j] = (short)h; lo[j] = (short)f2bf(v[j] - bf2f(h));
    }
}

// LDS-staged coalesced tile store: MFMA C-layout -> 4x 1KB contiguous dwordx4 stores.
template <bool RELU, bool STATS>
__device__ __forceinline__ void epi_tile(float* wl, int lane, const f32x4* acc,
                                         const float* bv, float* __restrict__ gout,
                                         int tile, double* ssum, double* ssq) {
    const int m = lane & 15, quad = lane >> 4;
#pragma unroll
    for (int ct = 0; ct < 4; ct++)
#pragma unroll
        for (int i = 0; i < 4; i++) {
            float val = acc[ct][i] + bv[ct];
            if (RELU) val = fmaxf(val, 0.f);
            wl[(quad * 4 + i) * 68 + ct * 16 + m] = val;
            if (STATS) { ssum[ct] += (double)val; ssq[ct] += (double)val * (double)val; }
        }
    asm volatile("s_waitcnt lgkmcnt(0)" ::: "memory");
#pragma unroll
    for (int j = 0; j < 4; j++) {
        int row = j * 4 + quad;
        f32x4 vv = *reinterpret_cast<const f32x4*>(wl + row * 68 + m * 4);
        *reinterpret_cast<f32x4*>(gout + ((size_t)(tile << 4) + row) * 64 + m * 4) = vv;
    }
}

// ---------- degree counts ----------
__global__ void k_deg(const int* __restrict__ ei, int* __restrict__ od, int* __restrict__ id) {
    int e = blockIdx.x * 256 + threadIdx.x;   // covers EE exactly
    atomAddI(&od[ei[e]], 1);
    atomAddI(&id[ei[EE + e]], 1);
}

// ---------- dual exclusive scan (block 0: dst-CSR, block 1: src-CSR) ----------
__global__ void __launch_bounds__(1024) k_scan2(const int* __restrict__ id, int* __restrict__ off,
                                                int* __restrict__ cursor,
                                                const int* __restrict__ od, int* __restrict__ off_s,
                                                int* __restrict__ cursor_s) {
    const int* cnt = (blockIdx.x == 0) ? id : od;
    int* o  = (blockIdx.x == 0) ? off : off_s;
    int* cu = (blockIdx.x == 0) ? cursor : cursor_s;
    __shared__ int part[1024];
    const int t = threadIdx.x;
    const int CH = (NN + 1023) / 1024;
    int base = t * CH, s = 0;
    for (int i = 0; i < CH; i++) { int idx = base + i; if (idx < NN) s += cnt[idx]; }
    part[t] = s;
    __syncthreads();
    if (t == 0) {
        int run = 0;
        for (int i = 0; i < 1024; i++) { int x = part[i]; part[i] = run; run += x; }
    }
    __syncthreads();
    int run = part[t];
    for (int i = 0; i < CH; i++) {
        int idx = base + i;
        if (idx < NN) { o[idx] = run; cu[idx] = run; run += cnt[idx]; }
    }
    if (t == 0) o[NN] = EE;
}

// ---------- generic single scan (for bucket counts) ----------
__global__ void __launch_bounds__(1024) k_scan(const int* __restrict__ cnt,
                                               int* __restrict__ off, int* __restrict__ cursor,
                                               int L, int total) {
    __shared__ int part[1024];
    const int t = threadIdx.x;
    const int CH = (L + 1023) / 1024;
    int base = t * CH, s = 0;
    for (int i = 0; i < CH; i++) { int idx = base + i; if (idx < L) s += cnt[idx]; }
    part[t] = s;
    __syncthreads();
    if (t == 0) {
        int run = 0;
        for (int i = 0; i < 1024; i++) { int x = part[i]; part[i] = run; run += x; }
    }
    __syncthreads();
    int run = part[t];
    for (int i = 0; i < CH; i++) {
        int idx = base + i;
        if (idx < L) { off[idx] = run; cursor[idx] = run; run += cnt[idx]; }
    }
}

// ---------- fill dst-sorted packed edge array: sd = src | (dst<<16) ----------
__global__ void k_fill(const int* __restrict__ ei, int* __restrict__ cursor,
                       unsigned int* __restrict__ sd_s) {
    int e = blockIdx.x * 256 + threadIdx.x;   // covers EE exactly
    int s = ei[e], d = ei[EE + e];
    int p = atomAddI(&cursor[d], 1);
    sd_s[p] = (unsigned int)s | ((unsigned int)d << 16);
}

// ---------- bucket-count (transposed: cntT[b*NCH + chunk]) ----------
__global__ void k_bcnt(const unsigned int* __restrict__ sd_s, int* __restrict__ cntT) {
    __shared__ int hist[NBUK];
    int t = threadIdx.x;
    if (t < NBUK) hist[t] = 0;
    __syncthreads();
    unsigned int sd = sd_s[blockIdx.x * 256 + t];
    int b = (int)(sd & 0xFFFFu) / 12500;
    atomicAdd(&hist[b], 1);
    __syncthreads();
    if (t < NBUK) cntT[t * NCH + blockIdx.x] = hist[t];
}

// ---------- stable bucket fill via 64-bit ballot ranking ----------
__global__ void k_bfill(const unsigned int* __restrict__ sd_s, const int* __restrict__ boff,
                        unsigned int* __restrict__ sd_b) {
    __shared__ int wcnt[4][NBUK];
    __shared__ int wbase[4][NBUK];
    int t = threadIdx.x, w = t >> 6, lane = t & 63;
    unsigned int sd = sd_s[blockIdx.x * 256 + t];
    int b = (int)(sd & 0xFFFFu) / 12500;
    unsigned long long mask[NBUK];
#pragma unroll
    for (int bb = 0; bb < NBUK; bb++) mask[bb] = __ballot(b == bb);
    if (lane < NBUK) wcnt[w][lane] = __popcll(mask[0] * 0 + mask[lane]);   // popc of mask[lane]
    __syncthreads();
    if (t < NBUK) {
        int run = boff[t * NCH + blockIdx.x];
        for (int ww = 0; ww < 4; ww++) { wbase[ww][t] = run; run += wcnt[ww][t]; }
    }
    __syncthreads();
    unsigned long long below = (lane == 0) ? 0ull : (~0ull >> (64 - lane));
    int rank = __popcll(mask[b] & below);
    sd_b[wbase[w][b] + rank] = sd;
}

// ---------- fill src-CSR permutation from bucketed list ----------
__global__ void k_fill2(const unsigned int* __restrict__ sd_b, int* __restrict__ cursor_s,
                        int* __restrict__ perm_s) {
    int p = blockIdx.x * 256 + threadIdx.x;   // covers EE exactly
    int s = (int)(sd_b[p] & 0xFFFFu);
    int q = atomAddI(&cursor_s[s], 1);
    perm_s[q] = p;
}

// ---------- dsum[n] = x[n] + sum_{e: dst=n} x[src_e]  (CSR, no atomics, 16-way MLP) ----------
__global__ void k_dsum_csr(const float* __restrict__ x, const int* __restrict__ off,
                           const unsigned int* __restrict__ sd_s, float* __restrict__ dsum) {
    int team = (blockIdx.x * 256 + threadIdx.x) >> 6;   // 12500 blocks x 4 = NN
    int c = threadIdx.x & 63;
    float a[16];
#pragma unroll
    for (int j = 0; j < 16; j++) a[j] = 0.f;
    a[0] = x[(size_t)team * 64 + c];
    int e = off[team], e1 = off[team + 1];
    for (; e + 15 < e1; e += 16)
#pragma unroll
        for (int j = 0; j < 16; j++) a[j] += x[(size_t)(sd_s[e + j] & 0xFFFFu) * 64 + c];
    for (; e + 3 < e1; e += 4)
#pragma unroll
        for (int j = 0; j < 4; j++) a[j] += x[(size_t)(sd_s[e + j] & 0xFFFFu) * 64 + c];
    for (; e < e1; e++) a[0] += x[(size_t)(sd_s[e] & 0xFFFFu) * 64 + c];
#pragma unroll
    for (int j = 0; j < 8; j++) a[j] += a[j + 8];
#pragma unroll
    for (int j = 0; j < 4; j++) a[j] += a[j + 4];
    dsum[(size_t)team * 64 + c] = (a[0] + a[1]) + (a[2] + a[3]);
}

// ---------- u = x@W_top, v = dsum@W_bot, u2 = dsum@W_top ----------
__global__ void k_uv3(const float* __restrict__ x, const float* __restrict__ dsum,
                      const float* __restrict__ W, float* __restrict__ u,
                      float* __restrict__ v, float* __restrict__ u2) {
    __shared__ float lds[4][16 * 68];
    const int lane = threadIdx.x & 63;
    const int wid = threadIdx.x >> 6;
    const int m = lane & 15, quad = lane >> 4;
    const int gwave = (blockIdx.x * blockDim.x + threadIdx.x) >> 6;
    const int nwaves = (gridDim.x * blockDim.x) >> 6;
    float* wl = lds[wid];

    bf16x8 wfh[4][4], wfl[4][4];
#pragma unroll
    for (int kk = 0; kk < 4; kk++)
#pragma unroll
        for (int ct = 0; ct < 4; ct++) {
            float wv[8];
#pragma unroll
            for (int j = 0; j < 8; j++)
                wv[j] = W[(kk * 32 + quad * 8 + j) * 64 + ct * 16 + m];
            split8r(wv, wfh[kk][ct], wfl[kk][ct]);
        }
    float zb[4] = {0.f, 0.f, 0.f, 0.f};

    for (int tile = gwave; tile < NT_N; tile += nwaves) {
        const int r = (tile << 4) + m;
        bf16x8 ah[4], al[4];
        split8(x    + (size_t)r * 64 + quad * 8,      ah[0], al[0]);
        split8(x    + (size_t)r * 64 + 32 + quad * 8, ah[1], al[1]);
        split8(dsum + (size_t)r * 64 + quad * 8,      ah[2], al[2]);
        split8(dsum + (size_t)r * 64 + 32 + quad * 8, ah[3], al[3]);

        f32x4 zero = {0.f, 0.f, 0.f, 0.f};
        f32x4 aU[4], aV[4], aU2[4];
#pragma unroll
        for (int ct = 0; ct < 4; ct++) {
            aU[ct] = zero; aV[ct] = zero; aU2[ct] = zero;
#pragma unroll
            for (int kk = 0; kk < 2; kk++) {
                aU[ct]  = __builtin_amdgcn_mfma_f32_16x16x32_bf16(al[kk],   wfh[kk][ct],   aU[ct],  0, 0, 0);
                aU[ct]  = __builtin_amdgcn_mfma_f32_16x16x32_bf16(ah[kk],   wfl[kk][ct],   aU[ct],  0, 0, 0);
                aU[ct]  = __builtin_amdgcn_mfma_f32_16x16x32_bf16(ah[kk],   wfh[kk][ct],   aU[ct],  0, 0, 0);
                aV[ct]  = __builtin_amdgcn_mfma_f32_16x16x32_bf16(al[kk+2], wfh[kk+2][ct], aV[ct],  0, 0, 0);
                aV[ct]  = __builtin_amdgcn_mfma_f32_16x16x32_bf16(ah[kk+2], wfl[kk+2][ct], aV[ct],  0, 0, 0);
                aV[ct]  = __builtin_amdgcn_mfma_f32_16x16x32_bf16(ah[kk+2], wfh[kk+2][ct], aV[ct],  0, 0, 0);
                aU2[ct] = __builtin_amdgcn_mfma_f32_16x16x32_bf16(al[kk+2], wfh[kk][ct],   aU2[ct], 0, 0, 0);
                aU2[ct] = __builtin_amdgcn_mfma_f32_16x16x32_bf16(ah[kk+2], wfl[kk][ct],   aU2[ct], 0, 0, 0);
                aU2[ct] = __builtin_amdgcn_mfma_f32_16x16x32_bf16(ah[kk+2], wfh[kk][ct],   aU2[ct], 0, 0, 0);
            }
        }
        epi_tile<false, false>(wl, lane, aU,  zb, u,  tile, nullptr, nullptr);
        epi_tile<false, false>(wl, lane, aV,  zb, v,  tile, nullptr, nullptr);
        epi_tile<false, false>(wl, lane, aU2, zb, u2, tile, nullptr, nullptr);
    }
}

// ---------- analytic stage-1 stats ----------
__global__ void k_stats1a(const float* __restrict__ u, const float* __restrict__ v,
                          const float* __restrict__ u2, const int* __restrict__ od,
                          const int* __restrict__ id, double* __restrict__ stats_raw) {
    __shared__ double lsum[4][64], lsq[4][64];
    int tid = threadIdx.x, c = tid & 63, w = tid >> 6;
    double a1 = 0.0, a2 = 0.0;
    for (int n = blockIdx.x * 4 + w; n < NN; n += gridDim.x * 4) {
        double uu = u[(size_t)n * 64 + c], vv = v[(size_t)n * 64 + c];
        double uu2 = u2[(size_t)n * 64 + c];
        double wod = 1.0 + od[n], wid = 1.0 + id[n];
        a1 += wod * uu + wid * vv;
        a2 += wod * uu * uu + wid * vv * vv + 2.0 * vv * uu2;
    }
    lsum[w][c] = a1; lsq[w][c] = a2;
    __syncthreads();
    if (w == 0) {
        a1 = lsum[0][c] + lsum[1][c] + lsum[2][c] + lsum[3][c];
        a2 = lsq[0][c] + lsq[1][c] + lsq[2][c] + lsq[3][c];
        atomAddD(&stats_raw[c], a1);
        atomAddD(&stats_raw[64 + c], a2);
    }
}

__global__ void k_fin1(const double* __restrict__ raw, const float* __restrict__ b,
                       float* __restrict__ fin, double inv_cnt) {
    int c = threadIdx.x;
    double m1 = raw[c] * inv_cnt;
    double var = raw[64 + c] * inv_cnt - m1 * m1;
    if (var < 0.0) var = 0.0;
    fin[c] = (float)(m1 + (double)b[c]);
    fin[64 + c] = (float)(1.0 / sqrt(var + 1e-5));
}

__global__ void k_fin(const double* __restrict__ raw, float* __restrict__ fin, double inv_cnt) {
    int c = threadIdx.x;
    double mean = raw[c] * inv_cnt;
    double var = raw[64 + c] * inv_cnt - mean * mean;
    if (var < 0.0) var = 0.0;
    fin[c] = (float)mean;
    fin[64 + c] = (float)(1.0 / sqrt(var + 1e-5));
}

// ---------- s_tab[n] = relu(bn1(u[n]+v[n]+b)) + sum_{e:dst=n} relu(bn1(u[src]+v[n]+b)) ----------
__global__ void k_s1_csr(const float* __restrict__ u, const float* __restrict__ v,
                         const int* __restrict__ off, const unsigned int* __restrict__ sd_s,
                         const float* __restrict__ b_un, const float* __restrict__ fin,
                         const float* __restrict__ g1, const float* __restrict__ be1,
                         float* __restrict__ s_tab) {
    int team = (blockIdx.x * 256 + threadIdx.x) >> 6;
    int c = threadIdx.x & 63;
    float sc = fin[64 + c] * g1[c];
    float tsh = (b_un[c] - fin[c]) * sc + be1[c];
    float vn = v[(size_t)team * 64 + c];
    float a[16];
#pragma unroll
    for (int j = 0; j < 16; j++) a[j] = 0.f;
    a[0] = fmaxf((u[(size_t)team * 64 + c] + vn) * sc + tsh, 0.f);   // self row
    int e = off[team], e1 = off[team + 1];
    for (; e + 15 < e1; e += 16)
#pragma unroll
        for (int j = 0; j < 16; j++)
            a[j] += fmaxf((u[(size_t)(sd_s[e + j] & 0xFFFFu) * 64 + c] + vn) * sc + tsh, 0.f);
    for (; e + 3 < e1; e += 4)
#pragma unroll
        for (int j = 0; j < 4; j++)
            a[j] += fmaxf((u[(size_t)(sd_s[e + j] & 0xFFFFu) * 64 + c] + vn) * sc + tsh, 0.f);
    for (; e < e1; e++) a[0] += fmaxf((u[(size_t)(sd_s[e] & 0xFFFFu) * 64 + c] + vn) * sc + tsh, 0.f);
#pragma unroll
    for (int j = 0; j < 8; j++) a[j] += a[j + 8];
#pragma unroll
    for (int j = 0; j < 4; j++) a[j] += a[j + 4];
    s_tab[(size_t)team * 64 + c] = (a[0] + a[1]) + (a[2] + a[3]);
}

// ---------- msg[n] = sum_{e:dst=n} s_tab[src_e] ----------
__global__ void k_msg_csr(const int* __restrict__ off, const unsigned int* __restrict__ sd_s,
                          const float* __restrict__ s_tab, float* __restrict__ msg) {
    int team = (blockIdx.x * 256 + threadIdx.x) >> 6;
    int c = threadIdx.x & 63;
    float a[16];
#pragma unroll
    for (int j = 0; j < 16; j++) a[j] = 0.f;
    int e = off[team], e1 = off[team + 1];
    for (; e + 15 < e1; e += 16)
#pragma unroll
        for (int j = 0; j < 16; j++) a[j] += s_tab[(size_t)(sd_s[e + j] & 0xFFFFu) * 64 + c];
    for (; e + 3 < e1; e += 4)
#pragma unroll
        for (int j = 0; j < 4; j++) a[j] += s_tab[(size_t)(sd_s[e + j] & 0xFFFFu) * 64 + c];
    for (; e < e1; e++) a[0] += s_tab[(size_t)(sd_s[e] & 0xFFFFu) * 64 + c];
#pragma unroll
    for (int j = 0; j < 8; j++) a[j] += a[j + 8];
#pragma unroll
    for (int j = 0; j < 4; j++) a[j] += a[j + 4];
    msg[(size_t)team * 64 + c] = (a[0] + a[1]) + (a[2] + a[3]);
}

// ---------- mb = msg @ W_gc[64:128]  (streaming, IN PLACE over msg) ----------
__global__ void k_mb(float* msg, const float* __restrict__ W) {
    __shared__ float lds[4][16 * 68];
    const int lane = threadIdx.x & 63;
    const int wid = threadIdx.x >> 6;
    const int m = lane & 15, quad = lane >> 4;
    const int gwave = (blockIdx.x * blockDim.x + threadIdx.x) >> 6;
    const int nwaves = (gridDim.x * blockDim.x) >> 6;
    float* wl = lds[wid];

    bf16x8 wfh[2][4], wfl[2][4];
#pragma unroll
    for (int kk = 0; kk < 2; kk++)
#pragma unroll
        for (int ct = 0; ct < 4; ct++) {
            float wv[8];
#pragma unroll
            for (int j = 0; j < 8; j++)
                wv[j] = W[(kk * 32 + quad * 8 + j) * 64 + ct * 16 + m];
            split8r(wv, wfh[kk][ct], wfl[kk][ct]);
        }
    float zb[4] = {0.f, 0.f, 0.f, 0.f};

    for (int tile = gwave; tile < NT_N; tile += nwaves) {
        const int r = (tile << 4) + m;
        bf16x8 ah[2], al[2];
        split8(msg + (size_t)r * 64 + quad * 8,      ah[0], al[0]);
        split8(msg + (size_t)r * 64 + 32 + quad * 8, ah[1], al[1]);

        f32x4 zero = {0.f, 0.f, 0.f, 0.f};
        f32x4 acc[4];
#pragma unroll
        for (int ct = 0; ct < 4; ct++) {
            acc[ct] = zero;
#pragma unroll
            for (int kk = 0; kk < 2; kk++) {
                acc[ct] = __builtin_amdgcn_mfma_f32_16x16x32_bf16(al[kk], wfh[kk][ct], acc[ct], 0, 0, 0);
                acc[ct] = __builtin_amdgcn_mfma_f32_16x16x32_bf16(ah[kk], wfl[kk][ct], acc[ct], 0, 0, 0);
                acc[ct] = __builtin_amdgcn_mfma_f32_16x16x32_bf16(ah[kk], wfh[kk][ct], acc[ct], 0, 0, 0);
            }
        }
        epi_tile<false, false>(wl, lane, acc, zb, msg, tile, nullptr, nullptr);
    }
}

// ---------- stage-2: h2_pre[row] = relu(bn1(u[sr]+v[dm]+b_un)) @ Wtop2 + mb[dm] + b_gc
// MODE 0: self tiles [0, NT_N) (sr=dm=r, sequential). MODE 1: one src-bucket's tile
// range (read from scanned bucket offsets) — launched per bucket so the 3.2 MB
// u-slice is temporally L2-resident (stream-order separation between buckets).
template <int MODE>
__global__ void k_ph0(const float* __restrict__ u, const float* __restrict__ v,
                      const float* __restrict__ mb, const unsigned int* __restrict__ sd_b,
                      const int* __restrict__ bo, int bukidx,
                      const float* __restrict__ W, const float* __restrict__ b_un,
                      const float* __restrict__ b_gc,
                      const float* __restrict__ fin1, const float* __restrict__ g1,
                      const float* __restrict__ be1,
                      float* __restrict__ h2pre, double* __restrict__ stats_raw) {
    __shared__ float lds[4][16 * 68];
    const int lane = threadIdx.x & 63;
    const int wid = threadIdx.x >> 6;
    const int m = lane & 15, quad = lane >> 4;
    const int gwave = (blockIdx.x * blockDim.x + threadIdx.x) >> 6;
    const int nwaves = (gridDim.x * blockDim.x) >> 6;
    float* wl = lds[wid];

    int tile0, tile1;
    if (MODE == 0) { tile0 = 0; tile1 = NT_N; }
    else {
        int e0 = bo[bukidx * NCH];
        int e1 = (bukidx + 1 < NBUK) ? bo[(bukidx + 1) * NCH] : EE;
        tile0 = (NN + e0 + 15) >> 4;
        tile1 = (NN + e1 + 15) >> 4;
    }

    bf16x8 wfh[2][4], wfl[2][4];
#pragma unroll
    for (int kk = 0; kk < 2; kk++)
#pragma unroll
        for (int ct = 0; ct < 4; ct++) {
            float wv[8];
#pragma unroll
            for (int j = 0; j < 8; j++)
                wv[j] = W[(kk * 32 + quad * 8 + j) * 64 + ct * 16 + m];
            split8r(wv, wfh[kk][ct], wfl[kk][ct]);
        }

    float bv[4];
#pragma unroll
    for (int ct = 0; ct < 4; ct++) bv[ct] = b_gc[ct * 16 + m];

    float s1f[2][8], t1f[2][8];
#pragma unroll
    for (int kk = 0; kk < 2; kk++)
#pragma unroll
        for (int j = 0; j < 8; j++) {
            int c = kk * 32 + quad * 8 + j;
            float sc = fin1[64 + c] * g1[c];
            s1f[kk][j] = sc;
            t1f[kk][j] = be1[c] + (b_un[c] - fin1[c]) * sc;
        }

    double ssum[4] = {0,0,0,0}, ssq[4] = {0,0,0,0};

    for (int tile = tile0 + gwave; tile < tile1; tile += nwaves) {
        const int r = (tile << 4) + m;
        int sr, dm;
        if (MODE == 0) { sr = r; dm = r; }
        else {
            unsigned int sd = sd_b[r - NN];
            sr = (int)(sd & 0xFFFFu);
            dm = (int)(sd >> 16);
        }

        bf16x8 ah[2], al[2];
#pragma unroll
        for (int kk = 0; kk < 2; kk++) {
            f32x4 u0 = *reinterpret_cast<const f32x4*>(u + (size_t)sr * 64 + kk * 32 + quad * 8);
            f32x4 u1 = *reinterpret_cast<const f32x4*>(u + (size_t)sr * 64 + kk * 32 + quad * 8 + 4);
            f32x4 v0 = *reinterpret_cast<const f32x4*>(v + (size_t)dm * 64 + kk * 32 + quad * 8);
            f32x4 v1 = *reinterpret_cast<const f32x4*>(v + (size_t)dm * 64 + kk * 32 + quad * 8 + 4);
            float tv[8];
#pragma unroll
            for (int j = 0; j < 4; j++) {
                tv[j]     = fmaxf((u0[j] + v0[j]) * s1f[kk][j]     + t1f[kk][j],     0.f);
                tv[4 + j] = fmaxf((u1[j] + v1[j]) * s1f[kk][4 + j] + t1f[kk][4 + j], 0.f);
            }
            split8r(tv, ah[kk], al[kk]);
        }

        f32x4 zero = {0.f, 0.f, 0.f, 0.f};
        f32x4 acc[4];
#pragma unroll
        for (int ct = 0; ct < 4; ct++) {
            acc[ct] = zero;
#pragma unroll
            for (int kk = 0; kk < 2; kk++) {
                acc[ct] = __builtin_amdgcn_mfma_f32_16x16x32_bf16(al[kk], wfh[kk][ct], acc[ct], 0, 0, 0);
                acc[ct] = __builtin_amdgcn_mfma_f32_16x16x32_bf16(ah[kk], wfl[kk][ct], acc[ct], 0, 0, 0);
                acc[ct] = __builtin_amdgcn_mfma_f32_16x16x32_bf16(ah[kk], wfh[kk][ct], acc[ct], 0, 0, 0);
            }
        }

        // add mb[dm_of_row] + b_gc per element, then stats + LDS-coalesced NT store
#pragma unroll
        for (int i = 0; i < 4; i++) {
            int dmv = __shfl(dm, (lane & 48) + quad * 4 + i, 64);   // dm of row quad*4+i
#pragma unroll
            for (int ct = 0; ct < 4; ct++) {
                float val = acc[ct][i] + bv[ct] + mb[(size_t)dmv * 64 + ct * 16 + m];
                wl[(quad * 4 + i) * 68 + ct * 16 + m] = val;
                ssum[ct] += (double)val;
                ssq[ct]  += (double)val * (double)val;
            }
        }
        asm volatile("s_waitcnt lgkmcnt(0)" ::: "memory");
#pragma unroll
        for (int j = 0; j < 4; j++) {
            int row = j * 4 + quad;
            f32x4 vv = *reinterpret_cast<const f32x4*>(wl + row * 68 + m * 4);
            __builtin_nontemporal_store(vv,
                reinterpret_cast<f32x4*>(h2pre + ((size_t)(tile << 4) + row) * 64 + m * 4));
        }
    }

#pragma unroll
    for (int ct = 0; ct < 4; ct++) {
        double sv = ssum[ct], qv = ssq[ct];
        sv += __shfl_xor(sv, 16, 64); sv += __shfl_xor(sv, 32, 64);
        qv += __shfl_xor(qv, 16, 64); qv += __shfl_xor(qv, 32, 64);
        if (quad == 0) {
            atomAddD(&stats_raw[ct * 16 + m], sv);
            atomAddD(&stats_raw[64 + ct * 16 + m], qv);
        }
    }
}

// ---------- agg[n] = relu(bn2(h2pre[n])) + sum_{q in src-CSR} relu(bn2(h2pre[NN+perm_s[q]])) ----------
__global__ void k_agg_csr(const float* __restrict__ h2pre, const int* __restrict__ off_s,
                          const int* __restrict__ perm_s, const float* __restrict__ fin2,
                          const float* __restrict__ g2, const float* __restrict__ be2,
                          float* __restrict__ agg) {
    int n = (blockIdx.x * 256 + threadIdx.x) >> 6;
    int c = threadIdx.x & 63;
    float sc = fin2[64 + c] * g2[c];
    float sh = be2[c] - fin2[c] * sc;
    float a[16];
#pragma unroll
    for (int j = 0; j < 16; j++) a[j] = 0.f;
    a[0] = fmaxf(h2pre[(size_t)n * 64 + c] * sc + sh, 0.f);   // self row
    int q = off_s[n], q1 = off_s[n + 1];
    for (; q + 15 < q1; q += 16)
#pragma unroll
        for (int j = 0; j < 16; j++) {
            float hv = __builtin_nontemporal_load(
                h2pre + (size_t)(NN + perm_s[q + j]) * 64 + c);
            a[j] += fmaxf(hv * sc + sh, 0.f);
        }
    for (; q + 3 < q1; q += 4)
#pragma unroll
        for (int j = 0; j < 4; j++) {
            float hv = __builtin_nontemporal_load(
                h2pre + (size_t)(NN + perm_s[q + j]) * 64 + c);
            a[j] += fmaxf(hv * sc + sh, 0.f);
        }
    for (; q < q1; q++) {
        float hv = __builtin_nontemporal_load(h2pre + (size_t)(NN + perm_s[q]) * 64 + c);
        a[0] += fmaxf(hv * sc + sh, 0.f);
    }
#pragma unroll
    for (int j = 0; j < 8; j++) a[j] += a[j + 8];
#pragma unroll
    for (int j = 0; j < 4; j++) a[j] += a[j + 4];
    agg[(size_t)n * 64 + c] = (a[0] + a[1]) + (a[2] + a[3]);
}

// ---------- stage 3: t_pre = [relu(bn2(h2pre[:N])), agg] @ W_tr + b_tr, stats3 ----------
__global__ void k_mm3(const float* __restrict__ h2pre, const float* __restrict__ agg,
                      const float* __restrict__ W, const float* __restrict__ bias,
                      const float* __restrict__ fin2, const float* __restrict__ g2,
                      const float* __restrict__ be2,
                      float* __restrict__ outp, double* __restrict__ stats_raw) {
    __shared__ float lds[4][16 * 68];
    const int lane = threadIdx.x & 63;
    const int wid = threadIdx.x >> 6;
    const int m = lane & 15, quad = lane >> 4;
    const int gwave = (blockIdx.x * blockDim.x + threadIdx.x) >> 6;
    const int nwaves = (gridDim.x * blockDim.x) >> 6;
    float* wl = lds[wid];

    bf16x8 wfh[4][4], wfl[4][4];
#pragma unroll
    for (int kk = 0; kk < 4; kk++)
#pragma unroll
        for (int ct = 0; ct < 4; ct++) {
            float wv[8];
#pragma unroll
            for (int j = 0; j < 8; j++)
                wv[j] = W[(kk * 32 + quad * 8 + j) * 64 + ct * 16 + m];
            split8r(wv, wfh[kk][ct], wfl[kk][ct]);
        }

    float bv[4];
#pragma unroll
    for (int ct = 0; ct < 4; ct++) bv[ct] = bias[ct * 16 + m];

    float s2f[2][8], t2f[2][8];
#pragma unroll
    for (int kk = 0; kk < 2; kk++)
#pragma unroll
        for (int j = 0; j < 8; j++) {
            int c = kk * 32 + quad * 8 + j;
            float sc = fin2[64 + c] * g2[c];
            s2f[kk][j] = sc;
            t2f[kk][j] = be2[c] - fin2[c] * sc;
        }

    double ssum[4] = {0,0,0,0}, ssq[4] = {0,0,0,0};

    for (int tile = gwave; tile < NT_N; tile += nwaves) {
        const int r = (tile << 4) + m;
        bf16x8 ah[4], al[4];
#pragma unroll
        for (int kk = 0; kk < 2; kk++) {
            f32x4 v0 = __builtin_nontemporal_load(
                reinterpret_cast<const f32x4*>(h2pre + (size_t)r * 64 + kk * 32 + quad * 8));
            f32x4 v1 = __builtin_nontemporal_load(
                reinterpret_cast<const f32x4*>(h2pre + (size_t)r * 64 + kk * 32 + quad * 8 + 4));
            float tv[8];
#pragma unroll
            for (int j = 0; j < 4; j++) {
                tv[j]     = fmaxf(v0[j] * s2f[kk][j]     + t2f[kk][j],     0.f);
                tv[4 + j] = fmaxf(v1[j] * s2f[kk][4 + j] + t2f[kk][4 + j], 0.f);
            }
            split8r(tv, ah[kk], al[kk]);
        }
        split8(agg + (size_t)r * 64 + quad * 8,      ah[2], al[2]);
        split8(agg + (size_t)r * 64 + 32 + quad * 8, ah[3], al[3]);

        f32x4 zero = {0.f, 0.f, 0.f, 0.f};
        f32x4 acc[4];
#pragma unroll
        for (int ct = 0; ct < 4; ct++) {
            acc[ct] = zero;
#pragma unroll
            for (int kk = 0; kk < 4; kk++)
                acc[ct] = __builtin_amdgcn_mfma_f32_16x16x32_bf16(al[kk], wfh[kk][ct], acc[ct], 0, 0, 0);
#pragma unroll
            for (int kk = 0; kk < 4; kk++)
                acc[ct] = __builtin_amdgcn_mfma_f32_16x16x32_bf16(ah[kk], wfl[kk][ct], acc[ct], 0, 0, 0);
#pragma unroll
            for (int kk = 0; kk < 4; kk++)
                acc[ct] = __builtin_amdgcn_mfma_f32_16x16x32_bf16(ah[kk], wfh[kk][ct], acc[ct], 0, 0, 0);
        }

        epi_tile<false, true>(wl, lane, acc, bv, outp, tile, ssum, ssq);
    }

#pragma unroll
    for (int ct = 0; ct < 4; ct++) {
        double sv = ssum[ct], qv = ssq[ct];
        sv += __shfl_xor(sv, 16, 64); sv += __shfl_xor(sv, 32, 64);
        qv += __shfl_xor(qv, 16, 64); qv += __shfl_xor(qv, 32, 64);
        if (quad == 0) {
            atomAddD(&stats_raw[ct * 16 + m], sv);
            atomAddD(&stats_raw[64 + ct * 16 + m], qv);
        }
    }
}

// ---------- stage 4 ----------
__global__ void k_mm4(const float* __restrict__ tpre, const float* __restrict__ W,
                      const float* __restrict__ bias, const float* __restrict__ fin3,
                      const float* __restrict__ g2, const float* __restrict__ be2,
                      float* __restrict__ outp, double* __restrict__ stats_raw) {
    __shared__ float lds[4][16 * 68];
    const int lane = threadIdx.x & 63;
    const int wid = threadIdx.x >> 6;
    const int m = lane & 15, quad = lane >> 4;
    const int gwave = (blockIdx.x * blockDim.x + threadIdx.x) >> 6;
    const int nwaves = (gridDim.x * blockDim.x) >> 6;
    float* wl = lds[wid];

    bf16x8 wfh[2][4], wfl[2][4];
#pragma unroll
    for (int kk = 0; kk < 2; kk++)
#pragma unroll
        for (int ct = 0; ct < 4; ct++) {
            float wv[8];
#pragma unroll
            for (int j = 0; j < 8; j++)
                wv[j] = W[(kk * 32 + quad * 8 + j) * 64 + ct * 16 + m];
            split8r(wv, wfh[kk][ct], wfl[kk][ct]);
        }

    float bv[4];
#pragma unroll
    for (int ct = 0; ct < 4; ct++) bv[ct] = bias[ct * 16 + m];

    float sc[2][8], sh[2][8];
#pragma unroll
    for (int kk = 0; kk < 2; kk++)
#pragma unroll
        for (int j = 0; j < 8; j++) {
            int c = kk * 32 + quad * 8 + j;
            float s = fin3[64 + c] * g2[c];
            sc[kk][j] = s;
            sh[kk][j] = be2[c] - fin3[c] * s;
        }

    double ssum[4] = {0,0,0,0}, ssq[4] = {0,0,0,0};

    for (int tile = gwave; tile < NT_N; tile += nwaves) {
        const int r = (tile << 4) + m;
        bf16x8 ah[2], al[2];
#pragma unroll
        for (int kk = 0; kk < 2; kk++) {
            f32x4 v0 = *reinterpret_cast<const f32x4*>(tpre + (size_t)r * 64 + kk * 32 + quad * 8);
            f32x4 v1 = *reinterpret_cast<const f32x4*>(tpre + (size_t)r * 64 + kk * 32 + quad * 8 + 4);
            float tv[8];
#pragma unroll
            for (int j = 0; j < 4; j++) {
                tv[j]     = fmaxf(v0[j] * sc[kk][j]     + sh[kk][j],     0.f);
                tv[4 + j] = fmaxf(v1[j] * sc[kk][4 + j] + sh[kk][4 + j], 0.f);
            }
            split8r(tv, ah[kk], al[kk]);
        }

        f32x4 zero = {0.f, 0.f, 0.f, 0.f};
        f32x4 acc[4];
#pragma unroll
        for (int ct = 0; ct < 4; ct++) {
            acc[ct] = zero;
#pragma unroll
            for (int kk = 0; kk < 2; kk++) {
                acc[ct] = __builtin_amdgcn_mfma_f32_16x16x32_bf16(al[kk], wfh[kk][ct], acc[ct], 0, 0, 0);
                acc[ct] = __builtin_amdgcn_mfma_f32_16x16x32_bf16(ah[kk], wfl[kk][ct], acc[ct], 0, 0, 0);
                acc[ct] = __builtin_amdgcn_mfma_f32_16x16x32_bf16(ah[kk], wfh[kk][ct], acc[ct], 0, 0, 0);
            }
        }

        epi_tile<true, true>(wl, lane, acc, bv, outp, tile, ssum, ssq);
    }

#pragma unroll
    for (int ct = 0; ct < 4; ct++) {
        double sv = ssum[ct], qv = ssq[ct];
        sv += __shfl_xor(sv, 16, 64); sv += __shfl_xor(sv, 32, 64);
        qv += __shfl_xor(qv, 16, 64); qv += __shfl_xor(qv, 32, 64);
        if (quad == 0) {
            atomAddD(&stats_raw[ct * 16 + m], sv);
            atomAddD(&stats_raw[64 + ct * 16 + m], qv);
        }
    }
}

// out = relu(bn(out_pre; stats4, g3, be3)) -> f32
__global__ void k_out(const float* __restrict__ op, const float* __restrict__ fin,
                      const float* __restrict__ g, const float* __restrict__ be,
                      float* __restrict__ out) {
    int i = blockIdx.x * 256 + threadIdx.x;   // covers NN*64 exactly
    int c = i & 63;
    out[i] = fmaxf((op[i] - fin[c]) * fin[64 + c] * g[c] + be[c], 0.f);
}

extern "C" void kernel_launch(void* const* d_in, const int* in_sizes, int n_in,
                              void* d_out, int out_size, void* d_ws, size_t ws_size,
                              hipStream_t stream) {
    const float* x    = (const float*)d_in[0];
    const int*   ei   = (const int*)d_in[1];
    const float* W_un = (const float*)d_in[2];
    const float* b_un = (const float*)d_in[3];
    const float* g1   = (const float*)d_in[4];
    const float* be1  = (const float*)d_in[5];
    const float* W_gc = (const float*)d_in[6];
    const float* b_gc = (const float*)d_in[7];
    const float* g2   = (const float*)d_in[8];
    const float* be2  = (const float*)d_in[9];
    const float* W_tr = (const float*)d_in[10];
    const float* b_tr = (const float*)d_in[11];
    const float* W_li = (const float*)d_in[12];
    const float* b_li = (const float*)d_in[13];
    const float* g3   = (const float*)d_in[14];
    const float* be3  = (const float*)d_in[15];

    float* ws = (float*)d_ws;
    const size_t FN = (size_t)NN * 64;           // 3.2M floats (12.8 MB)
    const size_t FR = (size_t)RR * 64;           // 54.4M floats (217.6 MB)
    float*  P0 = ws;
    float*  P1 = ws + FN;
    float*  P2 = ws + 2 * FN;
    float*  H  = ws + 3 * FN;
    float*  u      = P0;
    float*  v      = P1;
    float*  msg    = P2;          // becomes mb after k_mb (in place)
    float*  s_tab  = H;
    float*  dsum   = H + FN;
    float*  u2     = H + 2 * FN;
    float*  h2pre  = H;
    float*  agg    = P0;
    float*  tpre   = P1;
    float*  outpre = P2;
    double*       stats_raw = (double*)(H + FR);
    int*          od        = (int*)(stats_raw + 512);
    int*          id        = od + NN;
    int*          off       = id + NN;
    int*          cursor    = off + NN + 1;
    int*          off_s     = cursor + NN;
    int*          cursor_s  = off_s + NN + 1;
    unsigned int* sd_s      = (unsigned int*)(cursor_s + NN);   // packed src|dst<<16, dst-sorted
    unsigned int* sd_b      = sd_s + EE;                        // bucketed layout
    int*          perm_s    = (int*)(sd_b + EE);
    int*          bcnt      = perm_s + EE;                      // NBUK*NCH
    float*        stats_fin = (float*)(bcnt + NBUK * NCH + 2);

    // zero: stats_raw + od + id (contiguous)
    hipMemsetAsync(stats_raw, 0, 512 * sizeof(double) + 2 * NN * sizeof(int), stream);

    // build dst-sorted packed edge list, stable src-bucket sort, src-CSR perm
    k_deg  <<<3125, 256,  0, stream>>>(ei, od, id);
    k_scan2<<<2,    1024, 0, stream>>>(id, off, cursor, od, off_s, cursor_s);
    k_fill <<<3125, 256,  0, stream>>>(ei, cursor, sd_s);
    k_bcnt <<<NCH,  256,  0, stream>>>(sd_s, bcnt);
    k_scan <<<1,    1024, 0, stream>>>(bcnt, bcnt, bcnt, NBUK * NCH, EE);
    k_bfill<<<NCH,  256,  0, stream>>>(sd_s, bcnt, sd_b);
    k_fill2<<<3125, 256,  0, stream>>>(sd_b, cursor_s, perm_s);

    // stage 0 + per-node tables
    k_dsum_csr<<<12500, 256, 0, stream>>>(x, off, sd_s, dsum);
    k_uv3<<<512, 256, 0, stream>>>(x, dsum, W_un, u, v, u2);

    // stage-1: analytic stats, then CSR reductions
    k_stats1a<<<256, 256, 0, stream>>>(u, v, u2, od, id, stats_raw + 0);
    k_fin1<<<1, 64, 0, stream>>>(stats_raw + 0, b_un, stats_fin + 0, 1.0 / (double)RR);
    k_s1_csr<<<12500, 256, 0, stream>>>(u, v, off, sd_s, b_un, stats_fin + 0, g1, be1, s_tab);
    k_msg_csr<<<12500, 256, 0, stream>>>(off, sd_s, s_tab, msg);
    k_mb<<<512, 256, 0, stream>>>(msg, W_gc + 64 * 64);       // msg -> mb in place

    // stage-2: per-bucket launches -> temporal L2 residency of each 3.2 MB u-slice
    k_ph0<0><<<512, 256, 0, stream>>>(u, v, msg, sd_b, bcnt, 0, W_gc, b_un, b_gc,
                                      stats_fin + 0, g1, be1, h2pre, stats_raw + 128);
    for (int b = 0; b < NBUK; b++)
        k_ph0<1><<<1024, 256, 0, stream>>>(u, v, msg, sd_b, bcnt, b, W_gc, b_un, b_gc,
                                           stats_fin + 0, g1, be1, h2pre, stats_raw + 128);
    k_fin<<<1, 64, 0, stream>>>(stats_raw + 128, stats_fin + 128, 1.0 / (double)RR);
    k_agg_csr<<<12500, 256, 0, stream>>>(h2pre, off_s, perm_s, stats_fin + 128, g2, be2, agg);

    // stage 3
    k_mm3<<<512, 256, 0, stream>>>(h2pre, agg, W_tr, b_tr, stats_fin + 128, g2, be2,
                                   tpre, stats_raw + 256);
    k_fin<<<1, 64, 0, stream>>>(stats_raw + 256, stats_fin + 256, 1.0 / (double)NN);

    // stage 4
    k_mm4<<<512, 256, 0, stream>>>(tpre, W_li, b_li, stats_fin + 256, g2, be2,
                                   outpre, stats_raw + 384);
    k_fin<<<1, 64, 0, stream>>>(stats_raw + 384, stats_fin + 384, 1.0 / (double)NN);

    k_out<<<12500, 256, 0, stream>>>(outpre, stats_fin + 384, g3, be3, (float*)d_out);
}

// Round 15
// 1068.008 us; speedup vs baseline: 1.3506x; 1.3506x over previous
//
#include <hip/hip_runtime.h>
#include <cstdint>
#include <math.h>

// Problem sizes (fixed by the reference).
#define NN 50000
#define EE 800000
#define RR 850000      // NN + EE rows
#define NT_N 3125      // NN/16
#define NT_R 53125     // RR/16

typedef short  bf16x8 __attribute__((ext_vector_type(8)));
typedef float  f32x4  __attribute__((ext_vector_type(4)));

__device__ __forceinline__ float bf2f(unsigned short b) {
    unsigned int u = ((unsigned int)b) << 16;
    return __builtin_bit_cast(float, u);
}
__device__ __forceinline__ unsigned short f2bf(float f) {
    unsigned int u = __builtin_bit_cast(unsigned int, f);
    u = u + 0x7fffu + ((u >> 16) & 1u);
    return (unsigned short)(u >> 16);
}
__device__ __forceinline__ void atomAddF(float* p, float v) { unsafeAtomicAdd(p, v); }
__device__ __forceinline__ void atomAddD(double* p, double v) { unsafeAtomicAdd(p, v); }
__device__ __forceinline__ int atomAddI(int* p, int v) { return atomicAdd(p, v); }

// split 8 consecutive f32 into hi/lo bf16 fragments: hi+lo == v to ~2^-16 rel
__device__ __forceinline__ void split8(const float* p, bf16x8& hi, bf16x8& lo) {
    f32x4 v0 = *reinterpret_cast<const f32x4*>(p);
    f32x4 v1 = *reinterpret_cast<const f32x4*>(p + 4);
#pragma unroll
    for (int j = 0; j < 4; j++) {
        unsigned short h0 = f2bf(v0[j]);
        hi[j] = (short)h0; lo[j] = (short)f2bf(v0[j] - bf2f(h0));
        unsigned short h1 = f2bf(v1[j]);
        hi[4 + j] = (short)h1; lo[4 + j] = (short)f2bf(v1[j] - bf2f(h1));
    }
}
__device__ __forceinline__ void split8r(const float* v, bf16x8& hi, bf16x8& lo) {
#pragma unroll
    for (int j = 0; j < 8; j++) {
        unsigned short h = f2bf(v[j]);
        hi[j] = (short)h; lo[j] = (short)f2bf(v[j] - bf2f(h));
    }
}

// LDS-staged coalesced tile store: MFMA C-layout -> 4x 1KB contiguous dwordx4 stores.
template <bool RELU, bool STATS>
__device__ __forceinline__ void epi_tile(float* wl, int lane, const f32x4* acc,
                                         const float* bv, float* __restrict__ gout,
                                         int tile, double* ssum, double* ssq) {
    const int m = lane & 15, quad = lane >> 4;
#pragma unroll
    for (int ct = 0; ct < 4; ct++)
#pragma unroll
        for (int i = 0; i < 4; i++) {
            float val = acc[ct][i] + bv[ct];
            if (RELU) val = fmaxf(val, 0.f);
            wl[(quad * 4 + i) * 68 + ct * 16 + m] = val;
            if (STATS) { ssum[ct] += (double)val; ssq[ct] += (double)val * (double)val; }
        }
    asm volatile("s_waitcnt lgkmcnt(0)" ::: "memory");
#pragma unroll
    for (int j = 0; j < 4; j++) {
        int row = j * 4 + quad;
        f32x4 vv = *reinterpret_cast<const f32x4*>(wl + row * 68 + m * 4);
        *reinterpret_cast<f32x4*>(gout + ((size_t)(tile << 4) + row) * 64 + m * 4) = vv;
    }
}

// ---------- degree counts ----------
__global__ void k_deg(const int* __restrict__ ei, int* __restrict__ od, int* __restrict__ id) {
    int e = blockIdx.x * 256 + threadIdx.x;   // covers EE exactly
    atomAddI(&od[ei[e]], 1);
    atomAddI(&id[ei[EE + e]], 1);
}

// ---------- dual exclusive scan (block 0: dst-CSR, block 1: src-CSR) ----------
__global__ void __launch_bounds__(1024) k_scan2(const int* __restrict__ id, int* __restrict__ off,
                                                int* __restrict__ cursor,
                                                const int* __restrict__ od, int* __restrict__ off_s,
                                                int* __restrict__ cursor_s) {
    const int* cnt = (blockIdx.x == 0) ? id : od;
    int* o  = (blockIdx.x == 0) ? off : off_s;
    int* cu = (blockIdx.x == 0) ? cursor : cursor_s;
    __shared__ int part[1024];
    const int t = threadIdx.x;
    const int CH = (NN + 1023) / 1024;
    int base = t * CH, s = 0;
    for (int i = 0; i < CH; i++) { int idx = base + i; if (idx < NN) s += cnt[idx]; }
    part[t] = s;
    __syncthreads();
    if (t == 0) {
        int run = 0;
        for (int i = 0; i < 1024; i++) { int x = part[i]; part[i] = run; run += x; }
    }
    __syncthreads();
    int run = part[t];
    for (int i = 0; i < CH; i++) {
        int idx = base + i;
        if (idx < NN) { o[idx] = run; cu[idx] = run; run += cnt[idx]; }
    }
    if (t == 0) o[NN] = EE;
}

// ---------- fill dst-sorted packed edge array: sd = src | (dst<<16) ----------
__global__ void k_fill(const int* __restrict__ ei, int* __restrict__ cursor,
                       unsigned int* __restrict__ sd_s) {
    int e = blockIdx.x * 256 + threadIdx.x;   // covers EE exactly
    int s = ei[e], d = ei[EE + e];
    int p = atomAddI(&cursor[d], 1);
    sd_s[p] = (unsigned int)s | ((unsigned int)d << 16);
}

// ---------- fill src-CSR permutation: perm_s[q] = dst-order position p ----------
__global__ void k_fill2(const unsigned int* __restrict__ sd_s, int* __restrict__ cursor_s,
                        int* __restrict__ perm_s) {
    int p = blockIdx.x * 256 + threadIdx.x;   // covers EE exactly
    int s = (int)(sd_s[p] & 0xFFFFu);
    int q = atomAddI(&cursor_s[s], 1);
    perm_s[q] = p;
}

// ---------- dsum[n] = x[n] + sum_{e: dst=n} x[src_e]  (CSR, no atomics, 16-way MLP) ----------
__global__ void k_dsum_csr(const float* __restrict__ x, const int* __restrict__ off,
                           const unsigned int* __restrict__ sd_s, float* __restrict__ dsum) {
    int team = (blockIdx.x * 256 + threadIdx.x) >> 6;   // 12500 blocks x 4 = NN
    int c = threadIdx.x & 63;
    float a[16];
#pragma unroll
    for (int j = 0; j < 16; j++) a[j] = 0.f;
    a[0] = x[(size_t)team * 64 + c];
    int e = off[team], e1 = off[team + 1];
    for (; e + 15 < e1; e += 16)
#pragma unroll
        for (int j = 0; j < 16; j++) a[j] += x[(size_t)(sd_s[e + j] & 0xFFFFu) * 64 + c];
    for (; e + 3 < e1; e += 4)
#pragma unroll
        for (int j = 0; j < 4; j++) a[j] += x[(size_t)(sd_s[e + j] & 0xFFFFu) * 64 + c];
    for (; e < e1; e++) a[0] += x[(size_t)(sd_s[e] & 0xFFFFu) * 64 + c];
#pragma unroll
    for (int j = 0; j < 8; j++) a[j] += a[j + 8];
#pragma unroll
    for (int j = 0; j < 4; j++) a[j] += a[j + 4];
    dsum[(size_t)team * 64 + c] = (a[0] + a[1]) + (a[2] + a[3]);
}

// ---------- u = x@W_top, v = dsum@W_bot, u2 = dsum@W_top ----------
__global__ void k_uv3(const float* __restrict__ x, const float* __restrict__ dsum,
                      const float* __restrict__ W, float* __restrict__ u,
                      float* __restrict__ v, float* __restrict__ u2) {
    __shared__ float lds[4][16 * 68];
    const int lane = threadIdx.x & 63;
    const int wid = threadIdx.x >> 6;
    const int m = lane & 15, quad = lane >> 4;
    const int gwave = (blockIdx.x * blockDim.x + threadIdx.x) >> 6;
    const int nwaves = (gridDim.x * blockDim.x) >> 6;
    float* wl = lds[wid];

    bf16x8 wfh[4][4], wfl[4][4];
#pragma unroll
    for (int kk = 0; kk < 4; kk++)
#pragma unroll
        for (int ct = 0; ct < 4; ct++) {
            float wv[8];
#pragma unroll
            for (int j = 0; j < 8; j++)
                wv[j] = W[(kk * 32 + quad * 8 + j) * 64 + ct * 16 + m];
            split8r(wv, wfh[kk][ct], wfl[kk][ct]);
        }
    float zb[4] = {0.f, 0.f, 0.f, 0.f};

    for (int tile = gwave; tile < NT_N; tile += nwaves) {
        const int r = (tile << 4) + m;
        bf16x8 ah[4], al[4];
        split8(x    + (size_t)r * 64 + quad * 8,      ah[0], al[0]);
        split8(x    + (size_t)r * 64 + 32 + quad * 8, ah[1], al[1]);
        split8(dsum + (size_t)r * 64 + quad * 8,      ah[2], al[2]);
        split8(dsum + (size_t)r * 64 + 32 + quad * 8, ah[3], al[3]);

        f32x4 zero = {0.f, 0.f, 0.f, 0.f};
        f32x4 aU[4], aV[4], aU2[4];
#pragma unroll
        for (int ct = 0; ct < 4; ct++) {
            aU[ct] = zero; aV[ct] = zero; aU2[ct] = zero;
#pragma unroll
            for (int kk = 0; kk < 2; kk++) {
                aU[ct]  = __builtin_amdgcn_mfma_f32_16x16x32_bf16(al[kk],   wfh[kk][ct],   aU[ct],  0, 0, 0);
                aU[ct]  = __builtin_amdgcn_mfma_f32_16x16x32_bf16(ah[kk],   wfl[kk][ct],   aU[ct],  0, 0, 0);
                aU[ct]  = __builtin_amdgcn_mfma_f32_16x16x32_bf16(ah[kk],   wfh[kk][ct],   aU[ct],  0, 0, 0);
                aV[ct]  = __builtin_amdgcn_mfma_f32_16x16x32_bf16(al[kk+2], wfh[kk+2][ct], aV[ct],  0, 0, 0);
                aV[ct]  = __builtin_amdgcn_mfma_f32_16x16x32_bf16(ah[kk+2], wfl[kk+2][ct], aV[ct],  0, 0, 0);
                aV[ct]  = __builtin_amdgcn_mfma_f32_16x16x32_bf16(ah[kk+2], wfh[kk+2][ct], aV[ct],  0, 0, 0);
                aU2[ct] = __builtin_amdgcn_mfma_f32_16x16x32_bf16(al[kk+2], wfh[kk][ct],   aU2[ct], 0, 0, 0);
                aU2[ct] = __builtin_amdgcn_mfma_f32_16x16x32_bf16(ah[kk+2], wfl[kk][ct],   aU2[ct], 0, 0, 0);
                aU2[ct] = __builtin_amdgcn_mfma_f32_16x16x32_bf16(ah[kk+2], wfh[kk][ct],   aU2[ct], 0, 0, 0);
            }
        }
        epi_tile<false, false>(wl, lane, aU,  zb, u,  tile, nullptr, nullptr);
        epi_tile<false, false>(wl, lane, aV,  zb, v,  tile, nullptr, nullptr);
        epi_tile<false, false>(wl, lane, aU2, zb, u2, tile, nullptr, nullptr);
    }
}

// ---------- analytic stage-1 stats ----------
__global__ void k_stats1a(const float* __restrict__ u, const float* __restrict__ v,
                          const float* __restrict__ u2, const int* __restrict__ od,
                          const int* __restrict__ id, double* __restrict__ stats_raw) {
    __shared__ double lsum[4][64], lsq[4][64];
    int tid = threadIdx.x, c = tid & 63, w = tid >> 6;
    double a1 = 0.0, a2 = 0.0;
    for (int n = blockIdx.x * 4 + w; n < NN; n += gridDim.x * 4) {
        double uu = u[(size_t)n * 64 + c], vv = v[(size_t)n * 64 + c];
        double uu2 = u2[(size_t)n * 64 + c];
        double wod = 1.0 + od[n], wid = 1.0 + id[n];
        a1 += wod * uu + wid * vv;
        a2 += wod * uu * uu + wid * vv * vv + 2.0 * vv * uu2;
    }
    lsum[w][c] = a1; lsq[w][c] = a2;
    __syncthreads();
    if (w == 0) {
        a1 = lsum[0][c] + lsum[1][c] + lsum[2][c] + lsum[3][c];
        a2 = lsq[0][c] + lsq[1][c] + lsq[2][c] + lsq[3][c];
        atomAddD(&stats_raw[c], a1);
        atomAddD(&stats_raw[64 + c], a2);
    }
}

__global__ void k_fin1(const double* __restrict__ raw, const float* __restrict__ b,
                       float* __restrict__ fin, double inv_cnt) {
    int c = threadIdx.x;
    double m1 = raw[c] * inv_cnt;
    double var = raw[64 + c] * inv_cnt - m1 * m1;
    if (var < 0.0) var = 0.0;
    fin[c] = (float)(m1 + (double)b[c]);
    fin[64 + c] = (float)(1.0 / sqrt(var + 1e-5));
}

__global__ void k_fin(const double* __restrict__ raw, float* __restrict__ fin, double inv_cnt) {
    int c = threadIdx.x;
    double mean = raw[c] * inv_cnt;
    double var = raw[64 + c] * inv_cnt - mean * mean;
    if (var < 0.0) var = 0.0;
    fin[c] = (float)mean;
    fin[64 + c] = (float)(1.0 / sqrt(var + 1e-5));
}

// ---------- s_tab[n] = relu(bn1(u[n]+v[n]+b)) + sum_{e:dst=n} relu(bn1(u[src]+v[n]+b)) ----------
__global__ void k_s1_csr(const float* __restrict__ u, const float* __restrict__ v,
                         const int* __restrict__ off, const unsigned int* __restrict__ sd_s,
                         const float* __restrict__ b_un, const float* __restrict__ fin,
                         const float* __restrict__ g1, const float* __restrict__ be1,
                         float* __restrict__ s_tab) {
    int team = (blockIdx.x * 256 + threadIdx.x) >> 6;
    int c = threadIdx.x & 63;
    float sc = fin[64 + c] * g1[c];
    float tsh = (b_un[c] - fin[c]) * sc + be1[c];
    float vn = v[(size_t)team * 64 + c];
    float a[16];
#pragma unroll
    for (int j = 0; j < 16; j++) a[j] = 0.f;
    a[0] = fmaxf((u[(size_t)team * 64 + c] + vn) * sc + tsh, 0.f);   // self row
    int e = off[team], e1 = off[team + 1];
    for (; e + 15 < e1; e += 16)
#pragma unroll
        for (int j = 0; j < 16; j++)
            a[j] += fmaxf((u[(size_t)(sd_s[e + j] & 0xFFFFu) * 64 + c] + vn) * sc + tsh, 0.f);
    for (; e + 3 < e1; e += 4)
#pragma unroll
        for (int j = 0; j < 4; j++)
            a[j] += fmaxf((u[(size_t)(sd_s[e + j] & 0xFFFFu) * 64 + c] + vn) * sc + tsh, 0.f);
    for (; e < e1; e++) a[0] += fmaxf((u[(size_t)(sd_s[e] & 0xFFFFu) * 64 + c] + vn) * sc + tsh, 0.f);
#pragma unroll
    for (int j = 0; j < 8; j++) a[j] += a[j + 8];
#pragma unroll
    for (int j = 0; j < 4; j++) a[j] += a[j + 4];
    s_tab[(size_t)team * 64 + c] = (a[0] + a[1]) + (a[2] + a[3]);
}

// ---------- msg[n] = sum_{e:dst=n} s_tab[src_e] ----------
__global__ void k_msg_csr(const int* __restrict__ off, const unsigned int* __restrict__ sd_s,
                          const float* __restrict__ s_tab, float* __restrict__ msg) {
    int team = (blockIdx.x * 256 + threadIdx.x) >> 6;
    int c = threadIdx.x & 63;
    float a[16];
#pragma unroll
    for (int j = 0; j < 16; j++) a[j] = 0.f;
    int e = off[team], e1 = off[team + 1];
    for (; e + 15 < e1; e += 16)
#pragma unroll
        for (int j = 0; j < 16; j++) a[j] += s_tab[(size_t)(sd_s[e + j] & 0xFFFFu) * 64 + c];
    for (; e + 3 < e1; e += 4)
#pragma unroll
        for (int j = 0; j < 4; j++) a[j] += s_tab[(size_t)(sd_s[e + j] & 0xFFFFu) * 64 + c];
    for (; e < e1; e++) a[0] += s_tab[(size_t)(sd_s[e] & 0xFFFFu) * 64 + c];
#pragma unroll
    for (int j = 0; j < 8; j++) a[j] += a[j + 8];
#pragma unroll
    for (int j = 0; j < 4; j++) a[j] += a[j + 4];
    msg[(size_t)team * 64 + c] = (a[0] + a[1]) + (a[2] + a[3]);
}

// ---------- mb = msg @ W_gc[64:128]  (streaming, IN PLACE over msg) ----------
__global__ void k_mb(float* msg, const float* __restrict__ W) {
    __shared__ float lds[4][16 * 68];
    const int lane = threadIdx.x & 63;
    const int wid = threadIdx.x >> 6;
    const int m = lane & 15, quad = lane >> 4;
    const int gwave = (blockIdx.x * blockDim.x + threadIdx.x) >> 6;
    const int nwaves = (gridDim.x * blockDim.x) >> 6;
    float* wl = lds[wid];

    bf16x8 wfh[2][4], wfl[2][4];
#pragma unroll
    for (int kk = 0; kk < 2; kk++)
#pragma unroll
        for (int ct = 0; ct < 4; ct++) {
            float wv[8];
#pragma unroll
            for (int j = 0; j < 8; j++)
                wv[j] = W[(kk * 32 + quad * 8 + j) * 64 + ct * 16 + m];
            split8r(wv, wfh[kk][ct], wfl[kk][ct]);
        }
    float zb[4] = {0.f, 0.f, 0.f, 0.f};

    for (int tile = gwave; tile < NT_N; tile += nwaves) {
        const int r = (tile << 4) + m;
        bf16x8 ah[2], al[2];
        split8(msg + (size_t)r * 64 + quad * 8,      ah[0], al[0]);
        split8(msg + (size_t)r * 64 + 32 + quad * 8, ah[1], al[1]);

        f32x4 zero = {0.f, 0.f, 0.f, 0.f};
        f32x4 acc[4];
#pragma unroll
        for (int ct = 0; ct < 4; ct++) {
            acc[ct] = zero;
#pragma unroll
            for (int kk = 0; kk < 2; kk++) {
                acc[ct] = __builtin_amdgcn_mfma_f32_16x16x32_bf16(al[kk], wfh[kk][ct], acc[ct], 0, 0, 0);
                acc[ct] = __builtin_amdgcn_mfma_f32_16x16x32_bf16(ah[kk], wfl[kk][ct], acc[ct], 0, 0, 0);
                acc[ct] = __builtin_amdgcn_mfma_f32_16x16x32_bf16(ah[kk], wfh[kk][ct], acc[ct], 0, 0, 0);
            }
        }
        epi_tile<false, false>(wl, lane, acc, zb, msg, tile, nullptr, nullptr);
    }
}

// ---------- stage-2: h2_pre[row] = relu(bn1(u[sr]+v[dm]+b_un)) @ Wtop2 + mb[dm] + b_gc
// K=64; dst-sorted edge rows (v/mb near-uniform per tile; u random = L2/L3-latency
// floor, measured R11..R14: NT store/prefetch/bucketing all fail to beat ~316 us).
__global__ void k_ph0(const float* __restrict__ u, const float* __restrict__ v,
                      const float* __restrict__ mb, const unsigned int* __restrict__ sd_s,
                      const float* __restrict__ W, const float* __restrict__ b_un,
                      const float* __restrict__ b_gc,
                      const float* __restrict__ fin1, const float* __restrict__ g1,
                      const float* __restrict__ be1,
                      float* __restrict__ h2pre, double* __restrict__ stats_raw) {
    __shared__ float lds[4][16 * 68];
    const int lane = threadIdx.x & 63;
    const int wid = threadIdx.x >> 6;
    const int m = lane & 15, quad = lane >> 4;
    const int gwave = (blockIdx.x * blockDim.x + threadIdx.x) >> 6;
    const int nwaves = (gridDim.x * blockDim.x) >> 6;
    float* wl = lds[wid];

    bf16x8 wfh[2][4], wfl[2][4];
#pragma unroll
    for (int kk = 0; kk < 2; kk++)
#pragma unroll
        for (int ct = 0; ct < 4; ct++) {
            float wv[8];
#pragma unroll
            for (int j = 0; j < 8; j++)
                wv[j] = W[(kk * 32 + quad * 8 + j) * 64 + ct * 16 + m];
            split8r(wv, wfh[kk][ct], wfl[kk][ct]);
        }

    float bv[4];
#pragma unroll
    for (int ct = 0; ct < 4; ct++) bv[ct] = b_gc[ct * 16 + m];

    float s1f[2][8], t1f[2][8];
#pragma unroll
    for (int kk = 0; kk < 2; kk++)
#pragma unroll
        for (int j = 0; j < 8; j++) {
            int c = kk * 32 + quad * 8 + j;
            float sc = fin1[64 + c] * g1[c];
            s1f[kk][j] = sc;
            t1f[kk][j] = be1[c] + (b_un[c] - fin1[c]) * sc;
        }

    double ssum[4] = {0,0,0,0}, ssq[4] = {0,0,0,0};

    for (int tile = gwave; tile < NT_R; tile += nwaves) {
        const int r = (tile << 4) + m;
        const bool selftile = (tile < NT_N);
        unsigned int sd = selftile ? ((unsigned int)r | ((unsigned int)r << 16))
                                   : sd_s[r - NN];
        int sr = (int)(sd & 0xFFFFu);
        int dm = (int)(sd >> 16);

        bf16x8 ah[2], al[2];
#pragma unroll
        for (int kk = 0; kk < 2; kk++) {
            f32x4 u0 = *reinterpret_cast<const f32x4*>(u + (size_t)sr * 64 + kk * 32 + quad * 8);
            f32x4 u1 = *reinterpret_cast<const f32x4*>(u + (size_t)sr * 64 + kk * 32 + quad * 8 + 4);
            f32x4 v0 = *reinterpret_cast<const f32x4*>(v + (size_t)dm * 64 + kk * 32 + quad * 8);
            f32x4 v1 = *reinterpret_cast<const f32x4*>(v + (size_t)dm * 64 + kk * 32 + quad * 8 + 4);
            float tv[8];
#pragma unroll
            for (int j = 0; j < 4; j++) {
                tv[j]     = fmaxf((u0[j] + v0[j]) * s1f[kk][j]     + t1f[kk][j],     0.f);
                tv[4 + j] = fmaxf((u1[j] + v1[j]) * s1f[kk][4 + j] + t1f[kk][4 + j], 0.f);
            }
            split8r(tv, ah[kk], al[kk]);
        }

        f32x4 zero = {0.f, 0.f, 0.f, 0.f};
        f32x4 acc[4];
#pragma unroll
        for (int ct = 0; ct < 4; ct++) {
            acc[ct] = zero;
#pragma unroll
            for (int kk = 0; kk < 2; kk++) {
                acc[ct] = __builtin_amdgcn_mfma_f32_16x16x32_bf16(al[kk], wfh[kk][ct], acc[ct], 0, 0, 0);
                acc[ct] = __builtin_amdgcn_mfma_f32_16x16x32_bf16(ah[kk], wfl[kk][ct], acc[ct], 0, 0, 0);
                acc[ct] = __builtin_amdgcn_mfma_f32_16x16x32_bf16(ah[kk], wfh[kk][ct], acc[ct], 0, 0, 0);
            }
        }

        // add mb[dm_of_row] + b_gc per element, then stats + LDS-coalesced NT store
#pragma unroll
        for (int i = 0; i < 4; i++) {
            int dmv = __shfl(dm, (lane & 48) + quad * 4 + i, 64);   // dm of row quad*4+i
#pragma unroll
            for (int ct = 0; ct < 4; ct++) {
                float val = acc[ct][i] + bv[ct] + mb[(size_t)dmv * 64 + ct * 16 + m];
                wl[(quad * 4 + i) * 68 + ct * 16 + m] = val;
                ssum[ct] += (double)val;
                ssq[ct]  += (double)val * (double)val;
            }
        }
        asm volatile("s_waitcnt lgkmcnt(0)" ::: "memory");
#pragma unroll
        for (int j = 0; j < 4; j++) {
            int row = j * 4 + quad;
            f32x4 vv = *reinterpret_cast<const f32x4*>(wl + row * 68 + m * 4);
            __builtin_nontemporal_store(vv,
                reinterpret_cast<f32x4*>(h2pre + ((size_t)(tile << 4) + row) * 64 + m * 4));
        }
    }

#pragma unroll
    for (int ct = 0; ct < 4; ct++) {
        double sv = ssum[ct], qv = ssq[ct];
        sv += __shfl_xor(sv, 16, 64); sv += __shfl_xor(sv, 32, 64);
        qv += __shfl_xor(qv, 16, 64); qv += __shfl_xor(qv, 32, 64);
        if (quad == 0) {
            atomAddD(&stats_raw[ct * 16 + m], sv);
            atomAddD(&stats_raw[64 + ct * 16 + m], qv);
        }
    }
}

// ---------- agg[n] = relu(bn2(h2pre[n])) + sum_{q in src-CSR} relu(bn2(h2pre[NN+perm_s[q]])) ----------
__global__ void k_agg_csr(const float* __restrict__ h2pre, const int* __restrict__ off_s,
                          const int* __restrict__ perm_s, const float* __restrict__ fin2,
                          const float* __restrict__ g2, const float* __restrict__ be2,
                          float* __restrict__ agg) {
    int n = (blockIdx.x * 256 + threadIdx.x) >> 6;
    int c = threadIdx.x & 63;
    float sc = fin2[64 + c] * g2[c];
    float sh = be2[c] - fin2[c] * sc;
    float a[16];
#pragma unroll
    for (int j = 0; j < 16; j++) a[j] = 0.f;
    a[0] = fmaxf(h2pre[(size_t)n * 64 + c] * sc + sh, 0.f);   // self row
    int q = off_s[n], q1 = off_s[n + 1];
    for (; q + 15 < q1; q += 16)
#pragma unroll
        for (int j = 0; j < 16; j++) {
            float hv = __builtin_nontemporal_load(
                h2pre + (size_t)(NN + perm_s[q + j]) * 64 + c);
            a[j] += fmaxf(hv * sc + sh, 0.f);
        }
    for (; q + 3 < q1; q += 4)
#pragma unroll
        for (int j = 0; j < 4; j++) {
            float hv = __builtin_nontemporal_load(
                h2pre + (size_t)(NN + perm_s[q + j]) * 64 + c);
            a[j] += fmaxf(hv * sc + sh, 0.f);
        }
    for (; q < q1; q++) {
        float hv = __builtin_nontemporal_load(h2pre + (size_t)(NN + perm_s[q]) * 64 + c);
        a[0] += fmaxf(hv * sc + sh, 0.f);
    }
#pragma unroll
    for (int j = 0; j < 8; j++) a[j] += a[j + 8];
#pragma unroll
    for (int j = 0; j < 4; j++) a[j] += a[j + 4];
    agg[(size_t)n * 64 + c] = (a[0] + a[1]) + (a[2] + a[3]);
}

// ---------- stage 3: t_pre = [relu(bn2(h2pre[:N])), agg] @ W_tr + b_tr, stats3 ----------
__global__ void k_mm3(const float* __restrict__ h2pre, const float* __restrict__ agg,
                      const float* __restrict__ W, const float* __restrict__ bias,
                      const float* __restrict__ fin2, const float* __restrict__ g2,
                      const float* __restrict__ be2,
                      float* __restrict__ outp, double* __restrict__ stats_raw) {
    __shared__ float lds[4][16 * 68];
    const int lane = threadIdx.x & 63;
    const int wid = threadIdx.x >> 6;
    const int m = lane & 15, quad = lane >> 4;
    const int gwave = (blockIdx.x * blockDim.x + threadIdx.x) >> 6;
    const int nwaves = (gridDim.x * blockDim.x) >> 6;
    float* wl = lds[wid];

    bf16x8 wfh[4][4], wfl[4][4];
#pragma unroll
    for (int kk = 0; kk < 4; kk++)
#pragma unroll
        for (int ct = 0; ct < 4; ct++) {
            float wv[8];
#pragma unroll
            for (int j = 0; j < 8; j++)
                wv[j] = W[(kk * 32 + quad * 8 + j) * 64 + ct * 16 + m];
            split8r(wv, wfh[kk][ct], wfl[kk][ct]);
        }

    float bv[4];
#pragma unroll
    for (int ct = 0; ct < 4; ct++) bv[ct] = bias[ct * 16 + m];

    float s2f[2][8], t2f[2][8];
#pragma unroll
    for (int kk = 0; kk < 2; kk++)
#pragma unroll
        for (int j = 0; j < 8; j++) {
            int c = kk * 32 + quad * 8 + j;
            float sc = fin2[64 + c] * g2[c];
            s2f[kk][j] = sc;
            t2f[kk][j] = be2[c] - fin2[c] * sc;
        }

    double ssum[4] = {0,0,0,0}, ssq[4] = {0,0,0,0};

    for (int tile = gwave; tile < NT_N; tile += nwaves) {
        const int r = (tile << 4) + m;
        bf16x8 ah[4], al[4];
#pragma unroll
        for (int kk = 0; kk < 2; kk++) {
            f32x4 v0 = __builtin_nontemporal_load(
                reinterpret_cast<const f32x4*>(h2pre + (size_t)r * 64 + kk * 32 + quad * 8));
            f32x4 v1 = __builtin_nontemporal_load(
                reinterpret_cast<const f32x4*>(h2pre + (size_t)r * 64 + kk * 32 + quad * 8 + 4));
            float tv[8];
#pragma unroll
            for (int j = 0; j < 4; j++) {
                tv[j]     = fmaxf(v0[j] * s2f[kk][j]     + t2f[kk][j],     0.f);
                tv[4 + j] = fmaxf(v1[j] * s2f[kk][4 + j] + t2f[kk][4 + j], 0.f);
            }
            split8r(tv, ah[kk], al[kk]);
        }
        split8(agg + (size_t)r * 64 + quad * 8,      ah[2], al[2]);
        split8(agg + (size_t)r * 64 + 32 + quad * 8, ah[3], al[3]);

        f32x4 zero = {0.f, 0.f, 0.f, 0.f};
        f32x4 acc[4];
#pragma unroll
        for (int ct = 0; ct < 4; ct++) {
            acc[ct] = zero;
#pragma unroll
            for (int kk = 0; kk < 4; kk++)
                acc[ct] = __builtin_amdgcn_mfma_f32_16x16x32_bf16(al[kk], wfh[kk][ct], acc[ct], 0, 0, 0);
#pragma unroll
            for (int kk = 0; kk < 4; kk++)
                acc[ct] = __builtin_amdgcn_mfma_f32_16x16x32_bf16(ah[kk], wfl[kk][ct], acc[ct], 0, 0, 0);
#pragma unroll
            for (int kk = 0; kk < 4; kk++)
                acc[ct] = __builtin_amdgcn_mfma_f32_16x16x32_bf16(ah[kk], wfh[kk][ct], acc[ct], 0, 0, 0);
        }

        epi_tile<false, true>(wl, lane, acc, bv, outp, tile, ssum, ssq);
    }

#pragma unroll
    for (int ct = 0; ct < 4; ct++) {
        double sv = ssum[ct], qv = ssq[ct];
        sv += __shfl_xor(sv, 16, 64); sv += __shfl_xor(sv, 32, 64);
        qv += __shfl_xor(qv, 16, 64); qv += __shfl_xor(qv, 32, 64);
        if (quad == 0) {
            atomAddD(&stats_raw[ct * 16 + m], sv);
            atomAddD(&stats_raw[64 + ct * 16 + m], qv);
        }
    }
}

// ---------- stage 4 ----------
__global__ void k_mm4(const float* __restrict__ tpre, const float* __restrict__ W,
                      const float* __restrict__ bias, const float* __restrict__ fin3,
                      const float* __restrict__ g2, const float* __restrict__ be2,
                      float* __restrict__ outp, double* __restrict__ stats_raw) {
    __shared__ float lds[4][16 * 68];
    const int lane = threadIdx.x & 63;
    const int wid = threadIdx.x >> 6;
    const int m = lane & 15, quad = lane >> 4;
    const int gwave = (blockIdx.x * blockDim.x + threadIdx.x) >> 6;
    const int nwaves = (gridDim.x * blockDim.x) >> 6;
    float* wl = lds[wid];

    bf16x8 wfh[2][4], wfl[2][4];
#pragma unroll
    for (int kk = 0; kk < 2; kk++)
#pragma unroll
        for (int ct = 0; ct < 4; ct++) {
            float wv[8];
#pragma unroll
            for (int j = 0; j < 8; j++)
                wv[j] = W[(kk * 32 + quad * 8 + j) * 64 + ct * 16 + m];
            split8r(wv, wfh[kk][ct], wfl[kk][ct]);
        }

    float bv[4];
#pragma unroll
    for (int ct = 0; ct < 4; ct++) bv[ct] = bias[ct * 16 + m];

    float sc[2][8], sh[2][8];
#pragma unroll
    for (int kk = 0; kk < 2; kk++)
#pragma unroll
        for (int j = 0; j < 8; j++) {
            int c = kk * 32 + quad * 8 + j;
            float s = fin3[64 + c] * g2[c];
            sc[kk][j] = s;
            sh[kk][j] = be2[c] - fin3[c] * s;
        }

    double ssum[4] = {0,0,0,0}, ssq[4] = {0,0,0,0};

    for (int tile = gwave; tile < NT_N; tile += nwaves) {
        const int r = (tile << 4) + m;
        bf16x8 ah[2], al[2];
#pragma unroll
        for (int kk = 0; kk < 2; kk++) {
            f32x4 v0 = *reinterpret_cast<const f32x4*>(tpre + (size_t)r * 64 + kk * 32 + quad * 8);
            f32x4 v1 = *reinterpret_cast<const f32x4*>(tpre + (size_t)r * 64 + kk * 32 + quad * 8 + 4);
            float tv[8];
#pragma unroll
            for (int j = 0; j < 4; j++) {
                tv[j]     = fmaxf(v0[j] * sc[kk][j]     + sh[kk][j],     0.f);
                tv[4 + j] = fmaxf(v1[j] * sc[kk][4 + j] + sh[kk][4 + j], 0.f);
            }
            split8r(tv, ah[kk], al[kk]);
        }

        f32x4 zero = {0.f, 0.f, 0.f, 0.f};
        f32x4 acc[4];
#pragma unroll
        for (int ct = 0; ct < 4; ct++) {
            acc[ct] = zero;
#pragma unroll
            for (int kk = 0; kk < 2; kk++) {
                acc[ct] = __builtin_amdgcn_mfma_f32_16x16x32_bf16(al[kk], wfh[kk][ct], acc[ct], 0, 0, 0);
                acc[ct] = __builtin_amdgcn_mfma_f32_16x16x32_bf16(ah[kk], wfl[kk][ct], acc[ct], 0, 0, 0);
                acc[ct] = __builtin_amdgcn_mfma_f32_16x16x32_bf16(ah[kk], wfh[kk][ct], acc[ct], 0, 0, 0);
            }
        }

        epi_tile<true, true>(wl, lane, acc, bv, outp, tile, ssum, ssq);
    }

#pragma unroll
    for (int ct = 0; ct < 4; ct++) {
        double sv = ssum[ct], qv = ssq[ct];
        sv += __shfl_xor(sv, 16, 64); sv += __shfl_xor(sv, 32, 64);
        qv += __shfl_xor(qv, 16, 64); qv += __shfl_xor(qv, 32, 64);
        if (quad == 0) {
            atomAddD(&stats_raw[ct * 16 + m], sv);
            atomAddD(&stats_raw[64 + ct * 16 + m], qv);
        }
    }
}

// out = relu(bn(out_pre; stats4, g3, be3)) -> f32
__global__ void k_out(const float* __restrict__ op, const float* __restrict__ fin,
                      const float* __restrict__ g, const float* __restrict__ be,
                      float* __restrict__ out) {
    int i = blockIdx.x * 256 + threadIdx.x;   // covers NN*64 exactly
    int c = i & 63;
    out[i] = fmaxf((op[i] - fin[c]) * fin[64 + c] * g[c] + be[c], 0.f);
}

extern "C" void kernel_launch(void* const* d_in, const int* in_sizes, int n_in,
                              void* d_out, int out_size, void* d_ws, size_t ws_size,
                              hipStream_t stream) {
    const float* x    = (const float*)d_in[0];
    const int*   ei   = (const int*)d_in[1];
    const float* W_un = (const float*)d_in[2];
    const float* b_un = (const float*)d_in[3];
    const float* g1   = (const float*)d_in[4];
    const float* be1  = (const float*)d_in[5];
    const float* W_gc = (const float*)d_in[6];
    const float* b_gc = (const float*)d_in[7];
    const float* g2   = (const float*)d_in[8];
    const float* be2  = (const float*)d_in[9];
    const float* W_tr = (const float*)d_in[10];
    const float* b_tr = (const float*)d_in[11];
    const float* W_li = (const float*)d_in[12];
    const float* b_li = (const float*)d_in[13];
    const float* g3   = (const float*)d_in[14];
    const float* be3  = (const float*)d_in[15];

    float* ws = (float*)d_ws;
    const size_t FN = (size_t)NN * 64;           // 3.2M floats (12.8 MB)
    const size_t FR = (size_t)RR * 64;           // 54.4M floats (217.6 MB)
    float*  P0 = ws;
    float*  P1 = ws + FN;
    float*  P2 = ws + 2 * FN;
    float*  H  = ws + 3 * FN;
    float*  u      = P0;
    float*  v      = P1;
    float*  msg    = P2;          // becomes mb after k_mb (in place)
    float*  s_tab  = H;
    float*  dsum   = H + FN;
    float*  u2     = H + 2 * FN;
    float*  h2pre  = H;
    float*  agg    = P0;
    float*  tpre   = P1;
    float*  outpre = P2;
    double*       stats_raw = (double*)(H + FR);
    int*          od        = (int*)(stats_raw + 512);
    int*          id        = od + NN;
    int*          off       = id + NN;
    int*          cursor    = off + NN + 1;
    int*          off_s     = cursor + NN;
    int*          cursor_s  = off_s + NN + 1;
    unsigned int* sd_s      = (unsigned int*)(cursor_s + NN);   // packed src|dst<<16, dst-sorted
    int*          perm_s    = (int*)(sd_s + EE);
    float*        stats_fin = (float*)(perm_s + EE);

    // zero: stats_raw + od + id (contiguous)
    hipMemsetAsync(stats_raw, 0, 512 * sizeof(double) + 2 * NN * sizeof(int), stream);

    // build dst-sorted packed edge list + src-CSR permutation
    k_deg  <<<3125, 256,  0, stream>>>(ei, od, id);
    k_scan2<<<2,    1024, 0, stream>>>(id, off, cursor, od, off_s, cursor_s);
    k_fill <<<3125, 256,  0, stream>>>(ei, cursor, sd_s);
    k_fill2<<<3125, 256,  0, stream>>>(sd_s, cursor_s, perm_s);

    // stage 0 + per-node tables
    k_dsum_csr<<<12500, 256, 0, stream>>>(x, off, sd_s, dsum);
    k_uv3<<<512, 256, 0, stream>>>(x, dsum, W_un, u, v, u2);

    // stage-1: analytic stats, then CSR reductions
    k_stats1a<<<256, 256, 0, stream>>>(u, v, u2, od, id, stats_raw + 0);
    k_fin1<<<1, 64, 0, stream>>>(stats_raw + 0, b_un, stats_fin + 0, 1.0 / (double)RR);
    k_s1_csr<<<12500, 256, 0, stream>>>(u, v, off, sd_s, b_un, stats_fin + 0, g1, be1, s_tab);
    k_msg_csr<<<12500, 256, 0, stream>>>(off, sd_s, s_tab, msg);
    k_mb<<<512, 256, 0, stream>>>(msg, W_gc + 64 * 64);       // msg -> mb in place

    // stage-2: single gather pass (K=64, NT-stored h2pre + stats), then src-CSR aggregate
    k_ph0<<<2048, 256, 0, stream>>>(u, v, msg, sd_s, W_gc, b_un, b_gc,
                                    stats_fin + 0, g1, be1, h2pre, stats_raw + 128);
    k_fin<<<1, 64, 0, stream>>>(stats_raw + 128, stats_fin + 128, 1.0 / (double)RR);
    k_agg_csr<<<12500, 256, 0, stream>>>(h2pre, off_s, perm_s, stats_fin + 128, g2, be2, agg);

    // stage 3
    k_mm3<<<512, 256, 0, stream>>>(h2pre, agg, W_tr, b_tr, stats_fin + 128, g2, be2,
                                   tpre, stats_raw + 256);
    k_fin<<<1, 64, 0, stream>>>(stats_raw + 256, stats_fin + 256, 1.0 / (double)NN);

    // stage 4
    k_mm4<<<512, 256, 0, stream>>>(tpre, W_li, b_li, stats_fin + 256, g2, be2,
                                   outpre, stats_raw + 384);
    k_fin<<<1, 64, 0, stream>>>(stats_raw + 384, stats_fin + 384, 1.0 / (double)NN);

    k_out<<<12500, 256, 0, stream>>>(outpre, stats_fin + 384, g3, be3, (float*)d_out);
}